// Round 4
// baseline (2585.391 us; speedup 1.0000x reference)
//
#include <hip/hip_runtime.h>
#include <cstdint>
#include <cstddef>

// Problem constants (B,N,M,D fixed by the reference setup_inputs)
#define BB 8
#define NPTS 2048
#define DIM 64

typedef _Float16 f16x8 __attribute__((ext_vector_type(8)));
typedef float f32x4 __attribute__((ext_vector_type(4)));

// eps schedule: DIAMETER^2 * 0.25^k down to blur^2 = 0.0025 (9 entries)
static const float EPS_H[9] = {100.0f, 25.0f, 6.25f, 1.5625f, 0.390625f,
                               0.09765625f, 0.0244140625f, 0.006103515625f,
                               0.0025f};

#if __has_builtin(__builtin_amdgcn_exp2f)
static __device__ __forceinline__ float fexp2(float x) {
  return __builtin_amdgcn_exp2f(x);
}
#else
static __device__ __forceinline__ float fexp2(float x) {
  float r;
  asm("v_exp_f32 %0, %1" : "=v"(r) : "v"(x));
  return r;
}
#endif

struct SMTask {
  const _Float16* P;   // [B,2048,64] row-side points (output indexed by these)
  const _Float16* Q;   // [B,2048,64] reduce-side points
  const float* logw;   // [B,2048] log weights of Q side
  const float* pot;    // [B,2048] potential on Q side (nullptr at init)
  const float* qsq;    // [B,2048] |q|^2
  const float* psq;    // [B,2048] |p|^2
  const float* oldf;   // [B,2048] for 0.5*(old+new) averaging (nullptr = none)
  float* out;          // [B,2048]
};

// ---------------- prep kernels ----------------

__global__ __launch_bounds__(256) void norm_weights_k(
    const float* __restrict__ w, float* __restrict__ aout,
    float* __restrict__ logout, int n) {
  int b = blockIdx.x;
  const float* wb = w + (size_t)b * n;
  __shared__ float red[256];
  float s = 0.f;
  for (int i = threadIdx.x; i < n; i += 256) s += wb[i];
  red[threadIdx.x] = s;
  __syncthreads();
  for (int st = 128; st > 0; st >>= 1) {
    if (threadIdx.x < st) red[threadIdx.x] += red[threadIdx.x + st];
    __syncthreads();
  }
  float mass = red[0];
  if (mass == 0.f) mass = 1.f;
  float inv = 1.f / mass;
  for (int i = threadIdx.x; i < n; i += 256) {
    float av = wb[i] * inv;
    aout[(size_t)b * n + i] = av;
    logout[(size_t)b * n + i] = logf(av);
  }
}

// squared norm of each D=64 row + fp16 conversion: one wave per row
__global__ __launch_bounds__(256) void sqnorm_cvt_k(
    const float* __restrict__ X, float* __restrict__ sq,
    _Float16* __restrict__ Xh, int rows) {
  int row = blockIdx.x * 4 + (threadIdx.x >> 6);
  int lane = threadIdx.x & 63;
  if (row >= rows) return;
  float v = X[(size_t)row * DIM + lane];
  Xh[(size_t)row * DIM + lane] = (_Float16)v;
  float s = v * v;
  #pragma unroll
  for (int off = 32; off > 0; off >>= 1) s += __shfl_xor(s, off);
  if (lane == 0) sq[row] = s;
}

// ---------------- fused cost+softmin (two-phase LSE) ----------------
// out[b,r] = -eps*ln2*( log2 sum_m 2^{ hq[m] + S[r,m]*ie2 } ) + 0.5*psq[r]
// S[r,m] = dot(P_r, Q_m) (f16 MFMA, fp32 acc)
// hq[m] = logw[m]*log2e + pot[m]*ie2 - 0.5*qsq[m]*ie2,  ie2 = log2e/eps.
// Block = 4 waves; each wave owns a 16-row tile and sweeps all 2048 cols
// twice: phase A (row max), phase B (sum of exp2).
__global__ __launch_bounds__(256) void fused_softmin_k(
    SMTask t0, SMTask t1, SMTask t2, SMTask t3, float ie2, float neg_eps_ln2) {
  __shared__ float hq[NPTS];
  SMTask T = (blockIdx.z == 0) ? t0
           : (blockIdx.z == 1) ? t1
           : (blockIdx.z == 2) ? t2 : t3;
  const int b = blockIdx.y;
  const int tid = threadIdx.x;
  const float LOG2E = 1.4426950408889634f;
  {
    const float* lw = T.logw + (size_t)b * NPTS;
    const float* q2 = T.qsq + (size_t)b * NPTS;
    const float* pt = T.pot ? T.pot + (size_t)b * NPTS : nullptr;
    for (int m = tid; m < NPTS; m += 256) {
      float h = fmaf(lw[m], LOG2E, -0.5f * q2[m] * ie2);
      if (pt) h = fmaf(pt[m], ie2, h);
      hq[m] = h;
    }
  }
  __syncthreads();

  const int lane = tid & 63, wave = tid >> 6;
  const int fr = lane & 15;         // col-in-tile (phaseC) / row (A,B frags)
  const int fkg = (lane >> 4) * 8;  // k-offset group
  const int r0 = blockIdx.x * 64 + wave * 16;
  const _Float16* Pb = T.P + ((size_t)b * NPTS + r0) * DIM;
  const _Float16* Qb = T.Q + (size_t)b * NPTS * DIM;
  // A fragments: rows r0..r0+15, K=64 split into two K=32 chunks (kept live)
  f16x8 a0 = *(const f16x8*)(Pb + fr * DIM + fkg);
  f16x8 a1 = *(const f16x8*)(Pb + fr * DIM + fkg + 32);

  // ---- phase A: row max ----
  float mx[4] = {-3e38f, -3e38f, -3e38f, -3e38f};
  #pragma unroll 4
  for (int c = 0; c < NPTS / 16; ++c) {
    int m0 = c * 16;
    const _Float16* qrow = Qb + (size_t)(m0 + fr) * DIM + fkg;
    f16x8 b0 = *(const f16x8*)(qrow);
    f16x8 b1 = *(const f16x8*)(qrow + 32);
    f32x4 acc = {0.f, 0.f, 0.f, 0.f};
    acc = __builtin_amdgcn_mfma_f32_16x16x32_f16(a0, b0, acc, 0, 0, 0);
    acc = __builtin_amdgcn_mfma_f32_16x16x32_f16(a1, b1, acc, 0, 0, 0);
    float h = hq[m0 + fr];  // this lane's col m = m0+fr
    #pragma unroll
    for (int q = 0; q < 4; ++q)
      mx[q] = fmaxf(mx[q], fmaf(acc[q], ie2, h));
  }
  #pragma unroll
  for (int off = 1; off < 16; off <<= 1) {
    #pragma unroll
    for (int q = 0; q < 4; ++q) mx[q] = fmaxf(mx[q], __shfl_xor(mx[q], off));
  }

  // ---- phase B: sum of exp2(v - mx) ----
  float sm[4] = {0.f, 0.f, 0.f, 0.f};
  #pragma unroll 4
  for (int c = 0; c < NPTS / 16; ++c) {
    int m0 = c * 16;
    const _Float16* qrow = Qb + (size_t)(m0 + fr) * DIM + fkg;
    f16x8 b0 = *(const f16x8*)(qrow);
    f16x8 b1 = *(const f16x8*)(qrow + 32);
    f32x4 acc = {0.f, 0.f, 0.f, 0.f};
    acc = __builtin_amdgcn_mfma_f32_16x16x32_f16(a0, b0, acc, 0, 0, 0);
    acc = __builtin_amdgcn_mfma_f32_16x16x32_f16(a1, b1, acc, 0, 0, 0);
    float h = hq[m0 + fr];
    #pragma unroll
    for (int q = 0; q < 4; ++q)
      sm[q] += fexp2(fmaf(acc[q], ie2, h) - mx[q]);
  }
  #pragma unroll
  for (int off = 1; off < 16; off <<= 1) {
    #pragma unroll
    for (int q = 0; q < 4; ++q) sm[q] += __shfl_xor(sm[q], off);
  }

  if (fr == 0) {
    #pragma unroll
    for (int q = 0; q < 4; ++q) {
      int rl = (lane >> 4) * 4 + q;
      size_t oi = (size_t)b * NPTS + r0 + rl;
      float f = neg_eps_ln2 * (__log2f(sm[q]) + mx[q]) + 0.5f * T.psq[oi];
      if (T.oldf) f = 0.5f * (T.oldf[oi] + f);
      T.out[oi] = f;
    }
  }
}

// ---------------- epilogue ----------------
__global__ __launch_bounds__(256) void loss_k(
    const float* __restrict__ aW, const float* __restrict__ f_fin,
    const float* __restrict__ f_aa, const float* __restrict__ bW,
    const float* __restrict__ g_fin, const float* __restrict__ g_bb,
    float* __restrict__ out) {
  __shared__ float red[256];
  float s = 0.f;
  for (int i = threadIdx.x; i < BB * NPTS; i += 256)
    s += aW[i] * (f_fin[i] - f_aa[i]);
  for (int i = threadIdx.x; i < BB * NPTS; i += 256)
    s += bW[i] * (g_fin[i] - g_bb[i]);
  red[threadIdx.x] = s;
  __syncthreads();
  for (int st = 128; st > 0; st >>= 1) {
    if (threadIdx.x < st) red[threadIdx.x] += red[threadIdx.x + st];
    __syncthreads();
  }
  if (threadIdx.x == 0) out[0] = red[0] * (1.f / BB);
}

__global__ void write_val_k(float* out, float v) { out[0] = v; }

// ---------------- host ----------------

extern "C" void kernel_launch(void* const* d_in, const int* in_sizes, int n_in,
                              void* d_out, int out_size, void* d_ws,
                              size_t ws_size, hipStream_t stream) {
  (void)in_sizes; (void)n_in; (void)out_size;
  const float* X = (const float*)d_in[0];   // [B,N,D]
  const float* Y = (const float*)d_in[1];   // [B,M,D]
  const float* W1 = (const float*)d_in[2];  // [B,N]
  const float* W2 = (const float*)d_in[3];  // [B,M]
  float* out = (float*)d_out;

  char* base = (char*)d_ws;
  size_t off = 0;
  auto alloc_b = [&](size_t bytes) {
    void* r = base + off;
    off += (bytes + 255) & ~(size_t)255;
    return r;
  };
  const size_t nP = (size_t)BB * NPTS;
  _Float16* Xh = (_Float16*)alloc_b(nP * DIM * 2);
  _Float16* Yh = (_Float16*)alloc_b(nP * DIM * 2);
  float* x2 = (float*)alloc_b(nP * 4);
  float* y2 = (float*)alloc_b(nP * 4);
  float* aW = (float*)alloc_b(nP * 4);
  float* bW = (float*)alloc_b(nP * 4);
  float* la = (float*)alloc_b(nP * 4);
  float* lb = (float*)alloc_b(nP * 4);
  float* fba[2] = {(float*)alloc_b(nP * 4), (float*)alloc_b(nP * 4)};
  float* gab[2] = {(float*)alloc_b(nP * 4), (float*)alloc_b(nP * 4)};
  float* faa[2] = {(float*)alloc_b(nP * 4), (float*)alloc_b(nP * 4)};
  float* gbb[2] = {(float*)alloc_b(nP * 4), (float*)alloc_b(nP * 4)};
  if (ws_size < off) {
    write_val_k<<<1, 1, 0, stream>>>(out, -(float)(ws_size >> 20));
    return;
  }

  // prep
  norm_weights_k<<<BB, 256, 0, stream>>>(W1, aW, la, NPTS);
  norm_weights_k<<<BB, 256, 0, stream>>>(W2, bW, lb, NPTS);
  sqnorm_cvt_k<<<BB * NPTS / 4, 256, 0, stream>>>(X, x2, Xh, BB * NPTS);
  sqnorm_cvt_k<<<BB * NPTS / 4, 256, 0, stream>>>(Y, y2, Yh, BB * NPTS);

  const float LN2 = 0.6931471805599453f;
  const float LOG2E = 1.4426950408889634f;
  dim3 fg(NPTS / 64, BB, 4);

  auto launch4 = [&](SMTask A, SMTask B2, SMTask C, SMTask D2, float eps) {
    float ie2 = LOG2E / eps;
    float nel = -eps * LN2;
    fused_softmin_k<<<fg, 256, 0, stream>>>(A, B2, C, D2, ie2, nel);
  };

  // init at eps0 (no potential, no averaging)
  {
    float e = EPS_H[0];
    launch4(
        SMTask{Xh, Yh, lb, nullptr, y2, x2, nullptr, fba[0]},
        SMTask{Yh, Xh, la, nullptr, x2, y2, nullptr, gab[0]},
        SMTask{Xh, Xh, la, nullptr, x2, x2, nullptr, faa[0]},
        SMTask{Yh, Yh, lb, nullptr, y2, y2, nullptr, gbb[0]},
        e);
  }

  // annealing loop: symmetric averaged updates, double-buffered
  int cur = 0;
  for (int it = 0; it < 9; ++it) {
    float e = EPS_H[it];
    int nxt = cur ^ 1;
    launch4(
        SMTask{Xh, Yh, lb, gab[cur], y2, x2, fba[cur], fba[nxt]},
        SMTask{Yh, Xh, la, fba[cur], x2, y2, gab[cur], gab[nxt]},
        SMTask{Xh, Xh, la, faa[cur], x2, x2, faa[cur], faa[nxt]},
        SMTask{Yh, Yh, lb, gbb[cur], y2, y2, gbb[cur], gbb[nxt]},
        e);
    cur = nxt;
  }

  // final extrapolation at eps target (no averaging)
  {
    float e = EPS_H[8];
    int nxt = cur ^ 1;
    launch4(
        SMTask{Xh, Yh, lb, gab[cur], y2, x2, nullptr, fba[nxt]},
        SMTask{Yh, Xh, la, fba[cur], x2, y2, nullptr, gab[nxt]},
        SMTask{Xh, Xh, la, faa[cur], x2, x2, nullptr, faa[nxt]},
        SMTask{Yh, Yh, lb, gbb[cur], y2, y2, nullptr, gbb[nxt]},
        e);
    loss_k<<<1, 256, 0, stream>>>(aW, fba[nxt], faa[nxt], bW, gab[nxt],
                                  gbb[nxt], out);
  }
}

// Round 5
// 568.939 us; speedup vs baseline: 4.5442x; 4.5442x over previous
//
#include <hip/hip_runtime.h>
#include <cstdint>
#include <cstddef>

// Problem constants (B,N,M,D fixed by the reference setup_inputs)
#define BB 8
#define NPTS 2048
#define DIM 64
#define CK 128    // Q cols staged per chunk
#define RPW 32    // P rows per wave (2 row-groups of 16)
#define BROWS 128 // P rows per block (4 waves)

typedef _Float16 f16x8 __attribute__((ext_vector_type(8)));
typedef float f32x4 __attribute__((ext_vector_type(4)));

// eps schedule: DIAMETER^2 * 0.25^k down to blur^2 = 0.0025 (9 entries)
static const float EPS_H[9] = {100.0f, 25.0f, 6.25f, 1.5625f, 0.390625f,
                               0.09765625f, 0.0244140625f, 0.006103515625f,
                               0.0025f};

#if __has_builtin(__builtin_amdgcn_exp2f)
static __device__ __forceinline__ float fexp2(float x) {
  return __builtin_amdgcn_exp2f(x);
}
#else
static __device__ __forceinline__ float fexp2(float x) {
  float r;
  asm("v_exp_f32 %0, %1" : "=v"(r) : "v"(x));
  return r;
}
#endif

static __device__ __forceinline__ void gload_lds16(const void* g, void* l) {
  __builtin_amdgcn_global_load_lds(
      (const __attribute__((address_space(1))) void*)g,
      (__attribute__((address_space(3))) void*)l, 16, 0, 0);
}

struct SMTask {
  const _Float16* P;   // [B,2048,64] row-side points (output indexed by these)
  const _Float16* Q;   // [B,2048,64] reduce-side points
  const float* logw;   // [B,2048] log weights of Q side
  const float* pot;    // [B,2048] potential on Q side (nullptr at init)
  const float* qsq;    // [B,2048] |q|^2
  const float* psq;    // [B,2048] |p|^2
  const float* oldf;   // [B,2048] for 0.5*(old+new) averaging (nullptr = none)
  float* out;          // [B,2048]
};

// ---------------- prep kernels ----------------

__global__ __launch_bounds__(256) void norm_weights_k(
    const float* __restrict__ w, float* __restrict__ aout,
    float* __restrict__ logout, int n) {
  int b = blockIdx.x;
  const float* wb = w + (size_t)b * n;
  __shared__ float red[256];
  float s = 0.f;
  for (int i = threadIdx.x; i < n; i += 256) s += wb[i];
  red[threadIdx.x] = s;
  __syncthreads();
  for (int st = 128; st > 0; st >>= 1) {
    if (threadIdx.x < st) red[threadIdx.x] += red[threadIdx.x + st];
    __syncthreads();
  }
  float mass = red[0];
  if (mass == 0.f) mass = 1.f;
  float inv = 1.f / mass;
  for (int i = threadIdx.x; i < n; i += 256) {
    float av = wb[i] * inv;
    aout[(size_t)b * n + i] = av;
    logout[(size_t)b * n + i] = logf(av);
  }
}

// squared norm of each D=64 row + fp16 conversion: one wave per row
__global__ __launch_bounds__(256) void sqnorm_cvt_k(
    const float* __restrict__ X, float* __restrict__ sq,
    _Float16* __restrict__ Xh, int rows) {
  int row = blockIdx.x * 4 + (threadIdx.x >> 6);
  int lane = threadIdx.x & 63;
  if (row >= rows) return;
  float v = X[(size_t)row * DIM + lane];
  Xh[(size_t)row * DIM + lane] = (_Float16)v;
  float s = v * v;
  #pragma unroll
  for (int off = 32; off > 0; off >>= 1) s += __shfl_xor(s, off);
  if (lane == 0) sq[row] = s;
}

// ---------------- fused cost+softmin (LDS-staged, chunked online LSE) ------
// out[b,r] = -eps*ln2*( log2 sum_m 2^{ hq[m] + S[r,m]*ie2 } ) + 0.5*psq[r]
// S[r,m] = dot(P_r, Q_m) (f16 MFMA, fp32 acc)
// hq[m] = logw[m]*log2e + pot[m]*ie2 - 0.5*qsq[m]*ie2,  ie2 = log2e/eps.
// Block = 4 waves, 128 P-rows; Q swept in 128-col LDS chunks (double-buffered,
// global_load_lds staged with source pre-swizzle, XOR-swizzled ds_read).
__global__ __launch_bounds__(256) void fused_softmin_k(
    SMTask t0, SMTask t1, SMTask t2, SMTask t3, float ie2, float neg_eps_ln2) {
  __shared__ float hq[NPTS];                         // 8 KB
  __shared__ __align__(16) _Float16 qb[2][CK * DIM]; // 2 x 16 KB
  SMTask T = (blockIdx.z == 0) ? t0
           : (blockIdx.z == 1) ? t1
           : (blockIdx.z == 2) ? t2 : t3;
  const int b = blockIdx.y;
  const int tid = threadIdx.x;
  const float LOG2E = 1.4426950408889634f;
  {
    const float* lw = T.logw + (size_t)b * NPTS;
    const float* q2 = T.qsq + (size_t)b * NPTS;
    const float* pt = T.pot ? T.pot + (size_t)b * NPTS : nullptr;
    for (int m = tid; m < NPTS; m += 256) {
      float h = fmaf(lw[m], LOG2E, -0.5f * q2[m] * ie2);
      if (pt) h = fmaf(pt[m], ie2, h);
      hq[m] = h;
    }
  }

  const int lane = tid & 63, wave = tid >> 6;
  const _Float16* Qb = T.Q + (size_t)b * NPTS * DIM;

  // stage chunk -> qb[buf]: linear LDS dest, inverse-swizzled global source.
  // granule gid (16B) at LDS offset gid*16 holds Q[m0 + gid/8][8 halfs of
  // k-granule (gid%8)^((gid/8)&7)].
  auto stage = [&](int buf, int chunk) {
    int m0 = chunk * CK;
    #pragma unroll
    for (int r = 0; r < 4; ++r) {
      int gbase = r * 256 + wave * 64;
      int gid = gbase + lane;
      int row = gid >> 3;
      int kg = (gid & 7) ^ (row & 7);
      const _Float16* src = Qb + (size_t)(m0 + row) * DIM + kg * 8;
      _Float16* dst = &qb[buf][(size_t)gbase * 8];  // wave-uniform base
      gload_lds16(src, dst);
    }
  };

  const int fr = lane & 15;        // MFMA row/col index within fragment
  const int g0 = lane >> 4;        // k-granule group (0..3)
  const int r0 = blockIdx.x * BROWS + wave * RPW;
  const _Float16* Pb = T.P + ((size_t)b * NPTS + r0) * DIM;
  f16x8 a0[2], a1[2];
  #pragma unroll
  for (int rg = 0; rg < 2; ++rg) {
    a0[rg] = *(const f16x8*)(Pb + (rg * 16 + fr) * DIM + g0 * 8);
    a1[rg] = *(const f16x8*)(Pb + (rg * 16 + fr) * DIM + g0 * 8 + 32);
  }

  float mx[2][4], sm[2][4];
  #pragma unroll
  for (int rg = 0; rg < 2; ++rg)
    #pragma unroll
    for (int q = 0; q < 4; ++q) { mx[rg][q] = -3.0e38f; sm[rg][q] = 0.f; }

  stage(0, 0);
  __syncthreads();  // covers hq writes + chunk-0 staging (vmcnt drained)

  for (int c = 0; c < NPTS / CK; ++c) {
    int cur = c & 1;
    if (c + 1 < NPTS / CK) stage(cur ^ 1, c + 1);
    int m0 = c * CK;
    const char* qbase = (const char*)&qb[cur][0];

    f32x4 acc[2][8];
    float hs[8];
    #pragma unroll
    for (int s = 0; s < 8; ++s) {
      int row = s * 16 + fr;
      int byte0 = row * 128 + ((g0 ^ (row & 7)) << 4);
      int byte1 = row * 128 + (((g0 + 4) ^ (row & 7)) << 4);
      f16x8 b0 = *(const f16x8*)(qbase + byte0);
      f16x8 b1 = *(const f16x8*)(qbase + byte1);
      hs[s] = hq[m0 + s * 16 + fr];
      f32x4 z = {0.f, 0.f, 0.f, 0.f};
      #pragma unroll
      for (int rg = 0; rg < 2; ++rg) {
        f32x4 t = __builtin_amdgcn_mfma_f32_16x16x32_f16(a0[rg], b0, z, 0, 0, 0);
        acc[rg][s] = __builtin_amdgcn_mfma_f32_16x16x32_f16(a1[rg], b1, t, 0, 0, 0);
      }
    }
    #pragma unroll
    for (int rg = 0; rg < 2; ++rg) {
      #pragma unroll
      for (int q = 0; q < 4; ++q) {
        float v[8];
        #pragma unroll
        for (int s = 0; s < 8; ++s) v[s] = fmaf(acc[rg][s][q], ie2, hs[s]);
        float cmx = fmaxf(fmaxf(fmaxf(v[0], v[1]), fmaxf(v[2], v[3])),
                          fmaxf(fmaxf(v[4], v[5]), fmaxf(v[6], v[7])));
        float nm = fmaxf(mx[rg][q], cmx);
        sm[rg][q] *= fexp2(mx[rg][q] - nm);
        mx[rg][q] = nm;
        float t0s = fexp2(v[0] - nm) + fexp2(v[1] - nm);
        float t1s = fexp2(v[2] - nm) + fexp2(v[3] - nm);
        float t2s = fexp2(v[4] - nm) + fexp2(v[5] - nm);
        float t3s = fexp2(v[6] - nm) + fexp2(v[7] - nm);
        sm[rg][q] += (t0s + t1s) + (t2s + t3s);
      }
    }
    __syncthreads();  // drains staging vmcnt + protects buffer swap
  }

  // reduce (mx,sm) over the 16 fr lanes (cols) of each row group
  #pragma unroll
  for (int off = 1; off < 16; off <<= 1) {
    #pragma unroll
    for (int rg = 0; rg < 2; ++rg) {
      #pragma unroll
      for (int q = 0; q < 4; ++q) {
        float omx = __shfl_xor(mx[rg][q], off);
        float os = __shfl_xor(sm[rg][q], off);
        float nm = fmaxf(mx[rg][q], omx);
        sm[rg][q] = sm[rg][q] * fexp2(mx[rg][q] - nm) + os * fexp2(omx - nm);
        mx[rg][q] = nm;
      }
    }
  }
  if (fr == 0) {
    #pragma unroll
    for (int rg = 0; rg < 2; ++rg) {
      #pragma unroll
      for (int q = 0; q < 4; ++q) {
        int r = r0 + rg * 16 + g0 * 4 + q;
        size_t oi = (size_t)b * NPTS + r;
        float f = neg_eps_ln2 * (__log2f(sm[rg][q]) + mx[rg][q]) +
                  0.5f * T.psq[oi];
        if (T.oldf) f = 0.5f * (T.oldf[oi] + f);
        T.out[oi] = f;
      }
    }
  }
}

// ---------------- epilogue ----------------
__global__ __launch_bounds__(256) void loss_k(
    const float* __restrict__ aW, const float* __restrict__ f_fin,
    const float* __restrict__ f_aa, const float* __restrict__ bW,
    const float* __restrict__ g_fin, const float* __restrict__ g_bb,
    float* __restrict__ out) {
  __shared__ float red[256];
  float s = 0.f;
  for (int i = threadIdx.x; i < BB * NPTS; i += 256)
    s += aW[i] * (f_fin[i] - f_aa[i]);
  for (int i = threadIdx.x; i < BB * NPTS; i += 256)
    s += bW[i] * (g_fin[i] - g_bb[i]);
  red[threadIdx.x] = s;
  __syncthreads();
  for (int st = 128; st > 0; st >>= 1) {
    if (threadIdx.x < st) red[threadIdx.x] += red[threadIdx.x + st];
    __syncthreads();
  }
  if (threadIdx.x == 0) out[0] = red[0] * (1.f / BB);
}

__global__ void write_val_k(float* out, float v) { out[0] = v; }

// ---------------- host ----------------

extern "C" void kernel_launch(void* const* d_in, const int* in_sizes, int n_in,
                              void* d_out, int out_size, void* d_ws,
                              size_t ws_size, hipStream_t stream) {
  (void)in_sizes; (void)n_in; (void)out_size;
  const float* X = (const float*)d_in[0];   // [B,N,D]
  const float* Y = (const float*)d_in[1];   // [B,M,D]
  const float* W1 = (const float*)d_in[2];  // [B,N]
  const float* W2 = (const float*)d_in[3];  // [B,M]
  float* out = (float*)d_out;

  char* base = (char*)d_ws;
  size_t off = 0;
  auto alloc_b = [&](size_t bytes) {
    void* r = base + off;
    off += (bytes + 255) & ~(size_t)255;
    return r;
  };
  const size_t nP = (size_t)BB * NPTS;
  _Float16* Xh = (_Float16*)alloc_b(nP * DIM * 2);
  _Float16* Yh = (_Float16*)alloc_b(nP * DIM * 2);
  float* x2 = (float*)alloc_b(nP * 4);
  float* y2 = (float*)alloc_b(nP * 4);
  float* aW = (float*)alloc_b(nP * 4);
  float* bW = (float*)alloc_b(nP * 4);
  float* la = (float*)alloc_b(nP * 4);
  float* lb = (float*)alloc_b(nP * 4);
  float* fba[2] = {(float*)alloc_b(nP * 4), (float*)alloc_b(nP * 4)};
  float* gab[2] = {(float*)alloc_b(nP * 4), (float*)alloc_b(nP * 4)};
  float* faa[2] = {(float*)alloc_b(nP * 4), (float*)alloc_b(nP * 4)};
  float* gbb[2] = {(float*)alloc_b(nP * 4), (float*)alloc_b(nP * 4)};
  if (ws_size < off) {
    write_val_k<<<1, 1, 0, stream>>>(out, -(float)(ws_size >> 20));
    return;
  }

  // prep
  norm_weights_k<<<BB, 256, 0, stream>>>(W1, aW, la, NPTS);
  norm_weights_k<<<BB, 256, 0, stream>>>(W2, bW, lb, NPTS);
  sqnorm_cvt_k<<<BB * NPTS / 4, 256, 0, stream>>>(X, x2, Xh, BB * NPTS);
  sqnorm_cvt_k<<<BB * NPTS / 4, 256, 0, stream>>>(Y, y2, Yh, BB * NPTS);

  const float LN2 = 0.6931471805599453f;
  const float LOG2E = 1.4426950408889634f;
  dim3 fg(NPTS / BROWS, BB, 4);

  auto launch4 = [&](SMTask A, SMTask B2, SMTask C, SMTask D2, float eps) {
    float ie2 = LOG2E / eps;
    float nel = -eps * LN2;
    fused_softmin_k<<<fg, 256, 0, stream>>>(A, B2, C, D2, ie2, nel);
  };

  // init at eps0 (no potential, no averaging)
  {
    float e = EPS_H[0];
    launch4(
        SMTask{Xh, Yh, lb, nullptr, y2, x2, nullptr, fba[0]},
        SMTask{Yh, Xh, la, nullptr, x2, y2, nullptr, gab[0]},
        SMTask{Xh, Xh, la, nullptr, x2, x2, nullptr, faa[0]},
        SMTask{Yh, Yh, lb, nullptr, y2, y2, nullptr, gbb[0]},
        e);
  }

  // annealing loop: symmetric averaged updates, double-buffered
  int cur = 0;
  for (int it = 0; it < 9; ++it) {
    float e = EPS_H[it];
    int nxt = cur ^ 1;
    launch4(
        SMTask{Xh, Yh, lb, gab[cur], y2, x2, fba[cur], fba[nxt]},
        SMTask{Yh, Xh, la, fba[cur], x2, y2, gab[cur], gab[nxt]},
        SMTask{Xh, Xh, la, faa[cur], x2, x2, faa[cur], faa[nxt]},
        SMTask{Yh, Yh, lb, gbb[cur], y2, y2, gbb[cur], gbb[nxt]},
        e);
    cur = nxt;
  }

  // final extrapolation at eps target (no averaging)
  {
    float e = EPS_H[8];
    int nxt = cur ^ 1;
    launch4(
        SMTask{Xh, Yh, lb, gab[cur], y2, x2, nullptr, fba[nxt]},
        SMTask{Yh, Xh, la, fba[cur], x2, y2, nullptr, gab[nxt]},
        SMTask{Xh, Xh, la, faa[cur], x2, x2, nullptr, faa[nxt]},
        SMTask{Yh, Yh, lb, gbb[cur], y2, y2, nullptr, gbb[nxt]},
        e);
    loss_k<<<1, 256, 0, stream>>>(aW, fba[nxt], faa[nxt], bW, gab[nxt],
                                  gbb[nxt], out);
  }
}

// Round 6
// 482.796 us; speedup vs baseline: 5.3550x; 1.1784x over previous
//
#include <hip/hip_runtime.h>
#include <cstdint>
#include <cstddef>

// Problem constants (B,N,M,D fixed by the reference setup_inputs)
#define BB 8
#define NPTS 2048
#define DIM 64
#define CK 128    // Q cols staged per chunk
#define BROWS 64  // P rows per block (4 waves x 16 rows)

typedef _Float16 f16x8 __attribute__((ext_vector_type(8)));
typedef float f32x4 __attribute__((ext_vector_type(4)));

// eps schedule: DIAMETER^2 * 0.25^k down to blur^2 = 0.0025 (9 entries)
static const float EPS_H[9] = {100.0f, 25.0f, 6.25f, 1.5625f, 0.390625f,
                               0.09765625f, 0.0244140625f, 0.006103515625f,
                               0.0025f};

#if __has_builtin(__builtin_amdgcn_exp2f)
static __device__ __forceinline__ float fexp2(float x) {
  return __builtin_amdgcn_exp2f(x);
}
#else
static __device__ __forceinline__ float fexp2(float x) {
  float r;
  asm("v_exp_f32 %0, %1" : "=v"(r) : "v"(x));
  return r;
}
#endif

static __device__ __forceinline__ f32x4 vmax4(f32x4 a, f32x4 b) {
  f32x4 r;
  #pragma unroll
  for (int i = 0; i < 4; ++i) r[i] = fmaxf(a[i], b[i]);
  return r;
}

static __device__ __forceinline__ f32x4 vexp2_4(f32x4 a) {
  f32x4 r;
  #pragma unroll
  for (int i = 0; i < 4; ++i) r[i] = fexp2(a[i]);
  return r;
}

static __device__ __forceinline__ void gload_lds16(const void* g, void* l) {
  __builtin_amdgcn_global_load_lds(
      (const __attribute__((address_space(1))) void*)g,
      (__attribute__((address_space(3))) void*)l, 16, 0, 0);
}

struct SMTask {
  const _Float16* P;   // [B,2048,64] row-side points (output indexed by these)
  const _Float16* Q;   // [B,2048,64] reduce-side points
  const float* logw;   // [B,2048] log weights of Q side
  const float* pot;    // [B,2048] potential on Q side (nullptr at init)
  const float* qsq;    // [B,2048] |q|^2
  const float* psq;    // [B,2048] |p|^2
  const float* oldf;   // [B,2048] for 0.5*(old+new) averaging (nullptr = none)
  float* out;          // [B,2048]
};

// ---------------- prep kernels ----------------

__global__ __launch_bounds__(256) void norm_weights_k(
    const float* __restrict__ w, float* __restrict__ aout,
    float* __restrict__ logout, int n) {
  int b = blockIdx.x;
  const float* wb = w + (size_t)b * n;
  __shared__ float red[256];
  float s = 0.f;
  for (int i = threadIdx.x; i < n; i += 256) s += wb[i];
  red[threadIdx.x] = s;
  __syncthreads();
  for (int st = 128; st > 0; st >>= 1) {
    if (threadIdx.x < st) red[threadIdx.x] += red[threadIdx.x + st];
    __syncthreads();
  }
  float mass = red[0];
  if (mass == 0.f) mass = 1.f;
  float inv = 1.f / mass;
  for (int i = threadIdx.x; i < n; i += 256) {
    float av = wb[i] * inv;
    aout[(size_t)b * n + i] = av;
    logout[(size_t)b * n + i] = logf(av);
  }
}

// squared norm of each D=64 row + fp16 conversion: one wave per row
__global__ __launch_bounds__(256) void sqnorm_cvt_k(
    const float* __restrict__ X, float* __restrict__ sq,
    _Float16* __restrict__ Xh, int rows) {
  int row = blockIdx.x * 4 + (threadIdx.x >> 6);
  int lane = threadIdx.x & 63;
  if (row >= rows) return;
  float v = X[(size_t)row * DIM + lane];
  Xh[(size_t)row * DIM + lane] = (_Float16)v;
  float s = v * v;
  #pragma unroll
  for (int off = 32; off > 0; off >>= 1) s += __shfl_xor(s, off);
  if (lane == 0) sq[row] = s;
}

// ---------------- fused cost+softmin (LDS-staged, chunked online LSE) ------
// out[b,r] = -eps*ln2*( log2 sum_m 2^{ hq[m] + S[r,m]*ie2 } ) + 0.5*psq[r]
// S[r,m] = dot(P_r, Q_m) (f16 MFMA, fp32 acc)
// hq[m] = logw[m]*log2e + pot[m]*ie2 - 0.5*qsq[m]*ie2,  ie2 = log2e/eps.
// Block = 4 waves x 16 P-rows; Q swept in 128-col LDS chunks (double-buffered,
// global_load_lds staged with source pre-swizzle, XOR-swizzled ds_read).
// Online-LSE state is elementwise f32x4 (per-lane: 4 rows, same col slice).
__global__ __launch_bounds__(256, 4) void fused_softmin_k(
    SMTask t0, SMTask t1, SMTask t2, SMTask t3, float ie2, float neg_eps_ln2) {
  __shared__ float hq[NPTS];                         // 8 KB
  __shared__ __align__(16) _Float16 qb[2][CK * DIM]; // 2 x 16 KB
  SMTask T = (blockIdx.z == 0) ? t0
           : (blockIdx.z == 1) ? t1
           : (blockIdx.z == 2) ? t2 : t3;
  const int b = blockIdx.y;
  const int tid = threadIdx.x;
  const float LOG2E = 1.4426950408889634f;
  {
    const float* lw = T.logw + (size_t)b * NPTS;
    const float* q2 = T.qsq + (size_t)b * NPTS;
    const float* pt = T.pot ? T.pot + (size_t)b * NPTS : nullptr;
    for (int m = tid; m < NPTS; m += 256) {
      float h = fmaf(lw[m], LOG2E, -0.5f * q2[m] * ie2);
      if (pt) h = fmaf(pt[m], ie2, h);
      hq[m] = h;
    }
  }

  const int lane = tid & 63, wave = tid >> 6;
  const _Float16* Qb = T.Q + (size_t)b * NPTS * DIM;

  // stage chunk -> qb[buf]: linear LDS dest, inverse-swizzled global source.
  // granule gid (16B) at LDS offset gid*16 holds Q[m0 + gid/8][8 halfs of
  // k-granule (gid%8)^((gid/8)&7)].
  auto stage = [&](int buf, int chunk) {
    int m0 = chunk * CK;
    #pragma unroll
    for (int r = 0; r < 4; ++r) {
      int gbase = r * 256 + wave * 64;
      int gid = gbase + lane;
      int row = gid >> 3;
      int kg = (gid & 7) ^ (row & 7);
      const _Float16* src = Qb + (size_t)(m0 + row) * DIM + kg * 8;
      _Float16* dst = &qb[buf][(size_t)gbase * 8];  // wave-uniform base
      gload_lds16(src, dst);
    }
  };

  const int fr = lane & 15;        // MFMA row/col index within fragment
  const int g0 = lane >> 4;        // k-granule group (0..3)
  const int r0 = blockIdx.x * BROWS + wave * 16;
  const _Float16* Pb = T.P + ((size_t)b * NPTS + r0) * DIM;
  f16x8 a0 = *(const f16x8*)(Pb + fr * DIM + g0 * 8);
  f16x8 a1 = *(const f16x8*)(Pb + fr * DIM + g0 * 8 + 32);

  f32x4 mx4 = {-3.0e38f, -3.0e38f, -3.0e38f, -3.0e38f};
  f32x4 sm4 = {0.f, 0.f, 0.f, 0.f};

  stage(0, 0);
  __syncthreads();  // covers hq writes + chunk-0 staging (vmcnt drained)

  for (int c = 0; c < NPTS / CK; ++c) {
    int cur = c & 1;
    if (c + 1 < NPTS / CK) stage(cur ^ 1, c + 1);
    int m0 = c * CK;
    const char* qbase = (const char*)&qb[cur][0];

    f32x4 v4[8];
    f32x4 cmx = mx4;
    #pragma unroll
    for (int s = 0; s < 8; ++s) {
      int row = s * 16 + fr;
      int byte0 = row * 128 + ((g0 ^ (row & 7)) << 4);
      int byte1 = row * 128 + (((g0 + 4) ^ (row & 7)) << 4);
      f16x8 b0 = *(const f16x8*)(qbase + byte0);
      f16x8 b1 = *(const f16x8*)(qbase + byte1);
      float hs = hq[m0 + s * 16 + fr];
      f32x4 z = {0.f, 0.f, 0.f, 0.f};
      f32x4 t = __builtin_amdgcn_mfma_f32_16x16x32_f16(a0, b0, z, 0, 0, 0);
      f32x4 acc = __builtin_amdgcn_mfma_f32_16x16x32_f16(a1, b1, t, 0, 0, 0);
      v4[s] = acc * ie2 + hs;
      cmx = vmax4(cmx, v4[s]);
    }
    f32x4 resc = vexp2_4(mx4 - cmx);
    f32x4 esum = vexp2_4(v4[0] - cmx);
    #pragma unroll
    for (int s = 1; s < 8; ++s) esum += vexp2_4(v4[s] - cmx);
    sm4 = sm4 * resc + esum;
    mx4 = cmx;
    __syncthreads();  // drains staging vmcnt + protects buffer swap
  }

  // reduce (mx,sm) over the 16 fr lanes (cols) of each row group
  #pragma unroll
  for (int off = 1; off < 16; off <<= 1) {
    #pragma unroll
    for (int q = 0; q < 4; ++q) {
      float omx = __shfl_xor(mx4[q], off);
      float osm = __shfl_xor(sm4[q], off);
      float nm = fmaxf(mx4[q], omx);
      sm4[q] = sm4[q] * fexp2(mx4[q] - nm) + osm * fexp2(omx - nm);
      mx4[q] = nm;
    }
  }
  if (fr == 0) {
    #pragma unroll
    for (int q = 0; q < 4; ++q) {
      int r = r0 + g0 * 4 + q;
      size_t oi = (size_t)b * NPTS + r;
      float f = neg_eps_ln2 * (__log2f(sm4[q]) + mx4[q]) + 0.5f * T.psq[oi];
      if (T.oldf) f = 0.5f * (T.oldf[oi] + f);
      T.out[oi] = f;
    }
  }
}

// ---------------- epilogue (two-stage) ----------------
__global__ __launch_bounds__(256) void loss_part_k(
    const float* __restrict__ aW, const float* __restrict__ f_fin,
    const float* __restrict__ f_aa, const float* __restrict__ bW,
    const float* __restrict__ g_fin, const float* __restrict__ g_bb,
    float* __restrict__ part) {
  __shared__ float red[256];
  int i0 = blockIdx.x * 256 + threadIdx.x;
  float s = 0.f;
  for (int i = i0; i < BB * NPTS; i += 64 * 256)
    s += aW[i] * (f_fin[i] - f_aa[i]) + bW[i] * (g_fin[i] - g_bb[i]);
  red[threadIdx.x] = s;
  __syncthreads();
  for (int st = 128; st > 0; st >>= 1) {
    if (threadIdx.x < st) red[threadIdx.x] += red[threadIdx.x + st];
    __syncthreads();
  }
  if (threadIdx.x == 0) part[blockIdx.x] = red[0];
}

__global__ __launch_bounds__(64) void loss_fin_k(const float* __restrict__ part,
                                                 float* __restrict__ out) {
  float s = part[threadIdx.x];
  #pragma unroll
  for (int off = 32; off > 0; off >>= 1) s += __shfl_xor(s, off);
  if (threadIdx.x == 0) out[0] = s * (1.f / BB);
}

__global__ void write_val_k(float* out, float v) { out[0] = v; }

// ---------------- host ----------------

extern "C" void kernel_launch(void* const* d_in, const int* in_sizes, int n_in,
                              void* d_out, int out_size, void* d_ws,
                              size_t ws_size, hipStream_t stream) {
  (void)in_sizes; (void)n_in; (void)out_size;
  const float* X = (const float*)d_in[0];   // [B,N,D]
  const float* Y = (const float*)d_in[1];   // [B,M,D]
  const float* W1 = (const float*)d_in[2];  // [B,N]
  const float* W2 = (const float*)d_in[3];  // [B,M]
  float* out = (float*)d_out;

  char* base = (char*)d_ws;
  size_t off = 0;
  auto alloc_b = [&](size_t bytes) {
    void* r = base + off;
    off += (bytes + 255) & ~(size_t)255;
    return r;
  };
  const size_t nP = (size_t)BB * NPTS;
  _Float16* Xh = (_Float16*)alloc_b(nP * DIM * 2);
  _Float16* Yh = (_Float16*)alloc_b(nP * DIM * 2);
  float* x2 = (float*)alloc_b(nP * 4);
  float* y2 = (float*)alloc_b(nP * 4);
  float* aW = (float*)alloc_b(nP * 4);
  float* bW = (float*)alloc_b(nP * 4);
  float* la = (float*)alloc_b(nP * 4);
  float* lb = (float*)alloc_b(nP * 4);
  float* fba[2] = {(float*)alloc_b(nP * 4), (float*)alloc_b(nP * 4)};
  float* gab[2] = {(float*)alloc_b(nP * 4), (float*)alloc_b(nP * 4)};
  float* faa[2] = {(float*)alloc_b(nP * 4), (float*)alloc_b(nP * 4)};
  float* gbb[2] = {(float*)alloc_b(nP * 4), (float*)alloc_b(nP * 4)};
  float* part = (float*)alloc_b(64 * 4);
  if (ws_size < off) {
    write_val_k<<<1, 1, 0, stream>>>(out, -(float)(ws_size >> 20));
    return;
  }

  // prep
  norm_weights_k<<<BB, 256, 0, stream>>>(W1, aW, la, NPTS);
  norm_weights_k<<<BB, 256, 0, stream>>>(W2, bW, lb, NPTS);
  sqnorm_cvt_k<<<BB * NPTS / 4, 256, 0, stream>>>(X, x2, Xh, BB * NPTS);
  sqnorm_cvt_k<<<BB * NPTS / 4, 256, 0, stream>>>(Y, y2, Yh, BB * NPTS);

  const float LN2 = 0.6931471805599453f;
  const float LOG2E = 1.4426950408889634f;
  dim3 fg(NPTS / BROWS, BB, 4);

  auto launch4 = [&](SMTask A, SMTask B2, SMTask C, SMTask D2, float eps) {
    float ie2 = LOG2E / eps;
    float nel = -eps * LN2;
    fused_softmin_k<<<fg, 256, 0, stream>>>(A, B2, C, D2, ie2, nel);
  };

  // init at eps0 (no potential, no averaging)
  {
    float e = EPS_H[0];
    launch4(
        SMTask{Xh, Yh, lb, nullptr, y2, x2, nullptr, fba[0]},
        SMTask{Yh, Xh, la, nullptr, x2, y2, nullptr, gab[0]},
        SMTask{Xh, Xh, la, nullptr, x2, x2, nullptr, faa[0]},
        SMTask{Yh, Yh, lb, nullptr, y2, y2, nullptr, gbb[0]},
        e);
  }

  // annealing loop: symmetric averaged updates, double-buffered
  int cur = 0;
  for (int it = 0; it < 9; ++it) {
    float e = EPS_H[it];
    int nxt = cur ^ 1;
    launch4(
        SMTask{Xh, Yh, lb, gab[cur], y2, x2, fba[cur], fba[nxt]},
        SMTask{Yh, Xh, la, fba[cur], x2, y2, gab[cur], gab[nxt]},
        SMTask{Xh, Xh, la, faa[cur], x2, x2, faa[cur], faa[nxt]},
        SMTask{Yh, Yh, lb, gbb[cur], y2, y2, gbb[cur], gbb[nxt]},
        e);
    cur = nxt;
  }

  // final extrapolation at eps target (no averaging)
  {
    float e = EPS_H[8];
    int nxt = cur ^ 1;
    launch4(
        SMTask{Xh, Yh, lb, gab[cur], y2, x2, nullptr, fba[nxt]},
        SMTask{Yh, Xh, la, fba[cur], x2, y2, nullptr, gab[nxt]},
        SMTask{Xh, Xh, la, faa[cur], x2, x2, nullptr, faa[nxt]},
        SMTask{Yh, Yh, lb, gbb[cur], y2, y2, nullptr, gbb[nxt]},
        e);
    loss_part_k<<<64, 256, 0, stream>>>(aW, fba[nxt], faa[nxt], bW, gab[nxt],
                                        gbb[nxt], part);
    loss_fin_k<<<1, 64, 0, stream>>>(part, out);
  }
}